// Round 12
// baseline (154.275 us; speedup 1.0000x reference)
//
#include <hip/hip_runtime.h>

#define B_ 256
#define N_IN 1152
#define N_OUT 10
#define OJ 160                      // N_OUT * D_OUT
#define LOG2E 1.44269504088896340736f
#define NSTRIP 32                   // n-strips per block (32 strips x 16 j = 512 thr)
#define NK (N_IN/NSTRIP)            // 36 n per strip
#define SPAD 168                    // sred row stride (mod 32 = 8 -> strips hit distinct banks)

typedef __attribute__((ext_vector_type(4))) float f32x4;

// ---- DPP rotate-reduce over a 16-lane row (pure VALU) ----
template<int CTRL>
__device__ __forceinline__ float dpp_add(float xx) {
  int y = __builtin_amdgcn_mov_dpp(__float_as_int(xx), CTRL, 0xF, 0xF, false);
  return xx + __int_as_float(y);
}
__device__ __forceinline__ float row_sum16(float xx) {
  xx = dpp_add<0x128>(xx); xx = dpp_add<0x124>(xx);
  xx = dpp_add<0x122>(xx); xx = dpp_add<0x121>(xx);
  return xx;                        // every lane of the 16-row holds the sum
}

// One block = one batch. All 3 routing iterations in-block:
//   pass0: c uniform (0.1 folded into reduce) -> v1
//   pass1: logits = u.v1 -> v12 = v1 + v2   (vbuf kept in log2 domain)
//   pass2: logits = u.v12 -> out = squash(s3)
// u recomputed per pass in exact f32 (80 FMA per (n, j-lane)); W streamed,
// shared across all 256 blocks via L2/L3 (W = 5.9 MB << L3).
__global__ __launch_bounds__(512) void caps_onekernel(
    const float* __restrict__ x,    // (256,1152,8)
    const float* __restrict__ W,    // (1,1152,10,16,8)
    float* __restrict__ out) {      // (256,10,16)
  __shared__ float xs[N_IN*8];          // 36 KB: this batch's x
  __shared__ float sred[NSTRIP*SPAD];   // 21.5 KB: strip partials (padded)
  __shared__ float vbuf[OJ];            // running veff * log2e
  const int tid = threadIdx.x;
  const int b = blockIdx.x;
  const int strip = tid >> 4, j = tid & 15;

  // stage x[b] (coalesced 16B/lane)
  {
    const f32x4* xg = (const f32x4*)(x + (size_t)b*N_IN*8);
    f32x4* xl = (f32x4*)xs;
    for (int i = tid; i < N_IN*2; i += 512) xl[i] = xg[i];
  }
  __syncthreads();

  float v[N_OUT];                       // veff[o][j]*log2e (valid from pass 1)

  for (int pass = 0; pass < 3; ++pass) {
    float acc[N_OUT];
#pragma unroll
    for (int o=0;o<N_OUT;o++) acc[o] = 0.f;

    for (int k = 0; k < NK; ++k) {
      const int n = k*NSTRIP + strip;
      const f32x4 xa = *(const f32x4*)&xs[n*8];
      const f32x4 xb = *(const f32x4*)&xs[n*8+4];
      const float* Wp = &W[(size_t)n*1280 + j*8];
      float u[N_OUT];
#pragma unroll
      for (int o=0;o<N_OUT;o++) {      // u[o] = <W[n,o,j,:], x[b,n,:]>  (exact f32)
        const f32x4 wa = *(const f32x4*)(Wp + o*128);
        const f32x4 wb = *(const f32x4*)(Wp + o*128 + 4);
        u[o] = wa.x*xa.x + wa.y*xa.y + wa.z*xa.z + wa.w*xa.w
             + wb.x*xb.x + wb.y*xb.y + wb.z*xb.z + wb.w*xb.w;
      }
      if (pass == 0) {
#pragma unroll
        for (int o=0;o<N_OUT;o++) acc[o] += u[o];
      } else {
        float ez[N_OUT], Z = 0.f;
#pragma unroll
        for (int o=0;o<N_OUT;o++) {    // logit in log2 domain; 16-j DPP reduce
          ez[o] = exp2f(row_sum16(u[o]*v[o]));
          Z += ez[o];
        }
        const float invZ = __builtin_amdgcn_rcpf(Z);
#pragma unroll
        for (int o=0;o<N_OUT;o++) acc[o] += (ez[o]*invZ)*u[o];
      }
    }

    // strip-reduce: all threads deposit, 160 threads sum + squash
#pragma unroll
    for (int o=0;o<N_OUT;o++) sred[strip*SPAD + o*16 + j] = acc[o];
    __syncthreads();                                   // A
    if (tid < OJ) {                    // tid = o*16 + j
      float s = 0.f;
#pragma unroll 8
      for (int g=0; g<NSTRIP; ++g) s += sred[g*SPAD + tid];
      if (pass == 0) s *= 0.1f;        // uniform coupling 1/10
      const float sq = row_sum16(s*s); // ||s||^2 over j (16-lane row)
      const float vv = s * (sq/(1.f+sq)) * rsqrtf(sq + 1e-8f);
      if (pass == 2) out[(size_t)b*OJ + tid] = vv;
      else           vbuf[tid] = (pass == 0) ? vv*LOG2E : vbuf[tid] + vv*LOG2E;
    }
    __syncthreads();                                   // B
    if (pass < 2) {
#pragma unroll
      for (int o=0;o<N_OUT;o++) v[o] = vbuf[o*16 + j];
    }
    // sred safely rewritten next pass: every thread re-reads vbuf before
    // reaching its next sred write; summers finished sred reads before B.
  }
}

extern "C" void kernel_launch(void* const* d_in, const int* in_sizes, int n_in,
                              void* d_out, int out_size, void* d_ws, size_t ws_size,
                              hipStream_t stream) {
  const float* x = (const float*)d_in[0];   // (256,1152,8)
  const float* W = (const float*)d_in[1];   // (1,1152,10,16,8)
  float* out = (float*)d_out;               // (256,10,16)

  caps_onekernel<<<B_, 512, 0, stream>>>(x, W, out);
}

// Round 13
// 119.167 us; speedup vs baseline: 1.2946x; 1.2946x over previous
//
#include <hip/hip_runtime.h>

#define B_ 256
#define N_IN 1152
#define N_OUT 10
#define D_OUT 16
#define OJ 160                     // N_OUT * D_OUT
#define SN (B_*OJ)                 // 40960
#define LOG2E 1.44269504088896340736f
#define NPB 16                     // n's per block
#define NPW 4                      // n's per wave (4 waves/block)
#define NSG (N_IN/NPB)             // 72 partial groups (P = 11.8 MB, ~1.4 MB/XCD: L2-fit)
#define NP1BLK (NSG*16)            // 1152 pass1 blocks

typedef __attribute__((ext_vector_type(8))) short bf16x8;
typedef __attribute__((ext_vector_type(4))) float f32x4;

#define NW_ELEMS (N_IN*N_OUT*D_OUT)      // 184320 rows of 8 (W)
#define NX_ELEMS (B_*N_IN)               // 294912 rows of 8 (x)
#define NWB (NW_ELEMS/256)               // 720 W-pack blocks
#define NTILES ((N_IN/16)*(B_/16))       // 1152 x-transpose tiles

// ---- bf16 split helpers (RNE) ----
__device__ __forceinline__ unsigned short f2bf(float f) {
  unsigned u = __float_as_uint(f);
  u += 0x7fffu + ((u >> 16) & 1u);
  return (unsigned short)(u >> 16);
}
__device__ __forceinline__ float bf2f(unsigned short s) {
  return __uint_as_float(((unsigned)s) << 16);
}
__device__ __forceinline__ void split8(const float* p, bf16x8& vh, bf16x8& vl) {
  const float4 a = *(const float4*)p;
  const float4 b = *(const float4*)(p + 4);
  const float w[8] = {a.x,a.y,a.z,a.w,b.x,b.y,b.z,b.w};
#pragma unroll
  for (int e=0;e<8;e++){
    unsigned short hh = f2bf(w[e]);
    vh[e] = (short)hh;
    vl[e] = (short)f2bf(w[e] - bf2f(hh));
  }
}

// ---- DPP rotate-reduce over a 16-lane row ----
template<int CTRL>
__device__ __forceinline__ float dpp_add(float xx) {
  int y = __builtin_amdgcn_mov_dpp(__float_as_int(xx), CTRL, 0xF, 0xF, false);
  return xx + __int_as_float(y);
}
__device__ __forceinline__ float row_sum16(float xx) {
  xx = dpp_add<0x128>(xx); xx = dpp_add<0x124>(xx);
  xx = dpp_add<0x122>(xx); xx = dpp_add<0x121>(xx);
  return xx;
}
__device__ __forceinline__ float squash_elem(float t) {
  const float sq = row_sum16(t * t);
  return t * (sq / (1.f + sq)) * rsqrtf(sq + 1e-8f);
}

// ---- dispatch 1: three independent block ranges ----
//  [0, NP1BLK)          : pass1 in exact f32 VALU (no pack dependency, no LDS)
//  [NP1BLK, +NWB)       : W hi/lo bf16 split (linear)
//  [NP1BLK+NWB, +NTILES): x hi/lo split + 16x16 LDS transpose -> [n][b]
__global__ __launch_bounds__(256) void d1_fused(
    const float* __restrict__ W, const float* __restrict__ x,
    short* __restrict__ WH, short* __restrict__ WL,
    short* __restrict__ XH, short* __restrict__ XL,
    float* __restrict__ P) {
  const int bid = blockIdx.x, tid = threadIdx.x;
  if (bid < NP1BLK) {
    // ---- pass1: thread = (batch bb, dim j); all 16 n in-register ----
    const int sg = bid >> 4, bg = bid & 15;
    const int bb = tid >> 4, j = tid & 15;
    const int b = bg*16 + bb;
    const int n0 = sg*NPB;

    float acc[N_OUT];
#pragma unroll
    for (int o=0;o<N_OUT;o++) acc[o] = 0.f;

    const float* xp = &x[((size_t)b*N_IN + n0)*8];
    const float* Wp = &W[(size_t)n0*1280 + j*8];
    for (int nn=0; nn<NPB; ++nn) {
      const f32x4 xa = *(const f32x4*)xp;
      const f32x4 xb = *(const f32x4*)(xp+4);
#pragma unroll
      for (int o=0;o<N_OUT;o++) {       // u[o] = <W[n,o,j,:], x[b,n,:]> exact f32
        const f32x4 wa = *(const f32x4*)(Wp + o*128);
        const f32x4 wb = *(const f32x4*)(Wp + o*128 + 4);
        acc[o] += wa.x*xa.x + wa.y*xa.y + wa.z*xa.z + wa.w*xa.w
                + wb.x*xb.x + wb.y*xb.y + wb.z*xb.z + wb.w*xb.w;
      }
      xp += 8;
      Wp += 1280;
    }
    float* Pp = &P[(size_t)sg*SN + (size_t)b*OJ + j];
#pragma unroll
    for (int o=0;o<N_OUT;o++) Pp[o*16] = acc[o];
  } else if (bid < NP1BLK + NWB) {
    // ---- W-pack ----
    const int t = (bid - NP1BLK)*256 + tid;
    bf16x8 vh, vl; split8(W + (size_t)t*8, vh, vl);
    ((bf16x8*)WH)[t] = vh; ((bf16x8*)WL)[t] = vl;
  } else {
    // ---- x-pack (LDS-transposed 16x16 tile -> [n][b]) ----
    __shared__ bf16x8 TH[16*17], TL[16*17];
    const int tile = bid - NP1BLK - NWB;
    const int nt = tile >> 4, bt = tile & 15;
    const int nn = tid & 15, bb = tid >> 4;        // n fastest: coalesced reads
    bf16x8 vh, vl;
    split8(x + ((size_t)(bt*16+bb)*N_IN + nt*16+nn)*8, vh, vl);
    TH[nn*17 + bb] = vh; TL[nn*17 + bb] = vl;
    __syncthreads();
    const int bb2 = tid & 15, nn2 = tid >> 4;      // b fastest: coalesced writes
    const size_t o = (size_t)(nt*16+nn2)*B_ + bt*16 + bb2;
    ((bf16x8*)XH)[o] = TH[nn2*17 + bb2];
    ((bf16x8*)XL)[o] = TL[nn2*17 + bb2];
  }
}

// K-chunk trick: one 16x16x32 MFMA; lane's K-chunk c=l>>4 pulls A from
// [WH,WL,WH,WL] and B from [XH,XH,XL,XL] => exact (Wh+Wl)(xh+xl).
// C layout: col=lane&15=b, row=c*4+e=j.

// ---- pass 2/3: u via MFMA, logits = u.veff (log2 domain), softmax, partial ----
__global__ __launch_bounds__(256) void caps_pass23(const short* __restrict__ WH,
                                                   const short* __restrict__ WL,
                                                   const short* __restrict__ XH,
                                                   const short* __restrict__ XL,
                                                   const float* __restrict__ veff,
                                                   float* __restrict__ P) {
  __shared__ f32x4 red[3*640];         // 30 KB; lane-contiguous 16B slots: conflict-free
  const int tid = threadIdx.x, w = tid >> 6, l = tid & 63;
  const int bb = l & 15, c = l >> 4;
  const int b0 = blockIdx.y * 16;
  const int n0 = blockIdx.x * NPB + w * NPW;
  const short* Abase = (c & 1)  ? WL : WH;
  const short* Bbase = (c >> 1) ? XL : XH;

  f32x4 vj[N_OUT], acc[N_OUT];
  const f32x4 zz = {0.f,0.f,0.f,0.f};
  const float* vp = &veff[(size_t)(b0+bb)*OJ + c*4];
#pragma unroll
  for (int o=0;o<N_OUT;o++) { vj[o] = *(const f32x4*)&vp[o*16]; acc[o] = zz; }

  for (int nn=0; nn<NPW; ++nn) {
    const int n = n0 + nn;
    const bf16x8 bfrag = *(const bf16x8*)&Bbase[((size_t)n*B_ + b0 + bb)*8];
    const short* Ap = &Abase[(size_t)n*1280 + bb*8];
    f32x4 u[N_OUT];
#pragma unroll
    for (int o=0;o<N_OUT;o++) {
      const bf16x8 afrag = *(const bf16x8*)&Ap[o*128];
      u[o] = __builtin_amdgcn_mfma_f32_16x16x32_bf16(afrag, bfrag, zz, 0,0,0);
    }
    float ez[N_OUT], Z = 0.f;
#pragma unroll
    for (int o=0;o<N_OUT;o++) {
      float t = u[o][0]*vj[o][0] + u[o][1]*vj[o][1]
              + u[o][2]*vj[o][2] + u[o][3]*vj[o][3];
      t += __shfl_xor(t, 16);
      t += __shfl_xor(t, 32);
      ez[o] = exp2f(t);                // veff already in log2 domain
      Z += ez[o];
    }
    const float invZ = __builtin_amdgcn_rcpf(Z);   // approx rcp, ~1e-7 rel
#pragma unroll
    for (int o=0;o<N_OUT;o++) acc[o] += (ez[o] * invZ) * u[o];
  }

  if (w) {
#pragma unroll
    for (int o=0;o<N_OUT;o++) red[(w-1)*640 + o*64 + l] = acc[o];
  }
  __syncthreads();
  if (!w) {
    float* Pp = &P[((size_t)blockIdx.x*B_ + b0 + bb)*OJ + c*4];
#pragma unroll
    for (int o=0;o<N_OUT;o++) {
      acc[o] += red[o*64+l] + red[640+o*64+l] + red[1280+o*64+l];
      *(f32x4*)&Pp[o*16] = acc[o];
    }
  }
}

// ---- reduce partials over NSG + squash (+ optional vprev, output scaling) ----
__global__ __launch_bounds__(256) void caps_finish(const float* __restrict__ P, float scale,
                                                   const float* __restrict__ vprev,
                                                   float* __restrict__ vout, float lscale) {
  const int idx = blockIdx.x*256 + threadIdx.x;      // b*160 + o*16 + j
  float t = 0.f;
#pragma unroll 8
  for (int g=0; g<NSG; ++g) t += P[(size_t)g*SN + idx];
  t *= scale;
  float v = squash_elem(t) * lscale;
  if (vprev != nullptr) v += vprev[idx];
  vout[idx] = v;
}

extern "C" void kernel_launch(void* const* d_in, const int* in_sizes, int n_in,
                              void* d_out, int out_size, void* d_ws, size_t ws_size,
                              hipStream_t stream) {
  const float* x = (const float*)d_in[0];   // (256,1152,8)
  const float* W = (const float*)d_in[1];   // (1,1152,10,16,8)
  float* out = (float*)d_out;               // (256,10,16)

  float* P   = (float*)d_ws;                // NSG*SN floats = 11.8 MB
  float* v1  = P  + (size_t)NSG*SN;         // stored * log2e
  float* v12 = v1 + SN;                     // stored * log2e
  short* WH = (short*)(v12 + SN);
  short* WL = WH + (size_t)NW_ELEMS*8;
  short* XH = WL + (size_t)NW_ELEMS*8;
  short* XL = XH + (size_t)NX_ELEMS*8;      // total ws ~= 27.5 MB

  // d1: pass1 (exact f32, pack-independent) + W-pack + x-pack in ONE dispatch
  d1_fused<<<NP1BLK + NWB + NTILES, 256, 0, stream>>>(W, x, WH, WL, XH, XL, P);
  // d2: v1 = squash(0.1*s1)*log2e
  caps_finish<<<SN/256, 256, 0, stream>>>(P, 0.1f, nullptr, v1, LOG2E);
  // d3: logits = u.v1 -> P
  caps_pass23<<<dim3(NSG,16), 256, 0, stream>>>(WH, WL, XH, XL, v1, P);
  // d4: v12 = v1 + squash(s2)*log2e
  caps_finish<<<SN/256, 256, 0, stream>>>(P, 1.0f, v1, v12, LOG2E);
  // d5: logits = u.v12 -> P
  caps_pass23<<<dim3(NSG,16), 256, 0, stream>>>(WH, WL, XH, XL, v12, P);
  // d6: out = squash(s3)
  caps_finish<<<SN/256, 256, 0, stream>>>(P, 1.0f, nullptr, out, 1.0f);
}

// Round 14
// 85.881 us; speedup vs baseline: 1.7964x; 1.3876x over previous
//
#include <hip/hip_runtime.h>

#define B_ 256
#define N_IN 1152
#define N_OUT 10
#define D_OUT 16
#define OJ 160                     // N_OUT * D_OUT
#define SN (B_*OJ)                 // 40960
#define LOG2E 1.44269504088896340736f
#define NPB 16                     // n's per block
#define NPW 4                      // n's per wave (4 waves/block)
#define NSG (N_IN/NPB)             // 72 partial groups (P = 11.8 MB)
#define NPASSB (NSG*16)            // 1152 pass blocks

typedef __attribute__((ext_vector_type(8))) short bf16x8;
typedef __attribute__((ext_vector_type(4))) float f32x4;

#define NW_ELEMS (N_IN*N_OUT*D_OUT)      // 184320 rows of 8 (W)
#define NX_ELEMS (B_*N_IN)               // 294912 rows of 8 (x)
#define NWB (NW_ELEMS/256)               // 720 W-pack blocks
#define NTILES ((N_IN/16)*(B_/16))       // 1152 x-transpose tiles

// ---- bf16 split helpers (RNE) ----
__device__ __forceinline__ unsigned short f2bf(float f) {
  unsigned u = __float_as_uint(f);
  u += 0x7fffu + ((u >> 16) & 1u);
  return (unsigned short)(u >> 16);
}
__device__ __forceinline__ float bf2f(unsigned short s) {
  return __uint_as_float(((unsigned)s) << 16);
}
__device__ __forceinline__ void split8(const float* p, bf16x8& vh, bf16x8& vl) {
  const float4 a = *(const float4*)p;
  const float4 b = *(const float4*)(p + 4);
  const float w[8] = {a.x,a.y,a.z,a.w,b.x,b.y,b.z,b.w};
#pragma unroll
  for (int e=0;e<8;e++){
    unsigned short hh = f2bf(w[e]);
    vh[e] = (short)hh;
    vl[e] = (short)f2bf(w[e] - bf2f(hh));
  }
}

// ---- DPP rotate-reduce over a 16-lane row ----
template<int CTRL>
__device__ __forceinline__ float dpp_add(float xx) {
  int y = __builtin_amdgcn_mov_dpp(__float_as_int(xx), CTRL, 0xF, 0xF, false);
  return xx + __int_as_float(y);
}
__device__ __forceinline__ float row_sum16(float xx) {
  xx = dpp_add<0x128>(xx); xx = dpp_add<0x124>(xx);
  xx = dpp_add<0x122>(xx); xx = dpp_add<0x121>(xx);
  return xx;
}
__device__ __forceinline__ float squash_elem(float t) {
  const float sq = row_sum16(t * t);
  return t * (sq / (1.f + sq)) * rsqrtf(sq + 1e-8f);
}

// ---- bijective XCD-chunk swizzle (T1): linear bid -> (sg,bg) so that
// XCD k (= bid%8 under round-robin dispatch) owns sg in [9k, 9k+9), all bg.
// Per-XCD resident: 9 sg W-slices (0.7 MB) + x (2.4 MB) < 4 MB L2.
__device__ __forceinline__ void sgbg_map(int bid, int& sg, int& bg) {
  const int xcd = bid & 7, q = bid >> 3;   // q in [0,144)
  sg = xcd*9 + (q % 9);                    // [0,72)
  bg = q / 9;                              // [0,16)
}

// ---- pack: W linear; x via LDS-transposed 16x16 tiles -> [n][b] ----
__global__ __launch_bounds__(256) void pack_all(const float* __restrict__ W,
                                                const float* __restrict__ x,
                                                short* __restrict__ WH, short* __restrict__ WL,
                                                short* __restrict__ XH, short* __restrict__ XL) {
  const int bid = blockIdx.x, tid = threadIdx.x;
  if (bid < NWB) {
    const int t = bid*256 + tid;
    bf16x8 vh, vl; split8(W + (size_t)t*8, vh, vl);
    ((bf16x8*)WH)[t] = vh; ((bf16x8*)WL)[t] = vl;
  } else {
    __shared__ bf16x8 TH[16*17], TL[16*17];
    const int tile = bid - NWB;
    const int nt = tile >> 4, bt = tile & 15;
    const int nn = tid & 15, bb = tid >> 4;        // n fastest: coalesced reads
    bf16x8 vh, vl;
    split8(x + ((size_t)(bt*16+bb)*N_IN + nt*16+nn)*8, vh, vl);
    TH[nn*17 + bb] = vh; TL[nn*17 + bb] = vl;
    __syncthreads();
    const int bb2 = tid & 15, nn2 = tid >> 4;      // b fastest: coalesced writes
    const size_t o = (size_t)(nt*16+nn2)*B_ + bt*16 + bb2;
    ((bf16x8*)XH)[o] = TH[nn2*17 + bb2];
    ((bf16x8*)XL)[o] = TL[nn2*17 + bb2];
  }
}

// K-chunk trick: one 16x16x32 MFMA; lane's K-chunk c=l>>4 pulls A from
// [WH,WL,WH,WL] and B from [XH,XH,XL,XL] => exact (Wh+Wl)(xh+xl).
// C layout: col=lane&15=b, row=c*4+e=j.

// ---- pass 1: uniform coupling (0.1 folded into finish) ----
__global__ __launch_bounds__(256) void caps_pass1(const short* __restrict__ WH,
                                                  const short* __restrict__ WL,
                                                  const short* __restrict__ XH,
                                                  const short* __restrict__ XL,
                                                  float* __restrict__ P) {
  __shared__ f32x4 red[3*640];         // 30 KB; lane-contiguous 16B slots: conflict-free
  int sg, bg; sgbg_map(blockIdx.x, sg, bg);
  const int tid = threadIdx.x, w = tid >> 6, l = tid & 63;
  const int bb = l & 15, c = l >> 4;
  const int b0 = bg * 16;
  const int n0 = sg * NPB + w * NPW;
  const short* Abase = (c & 1)  ? WL : WH;
  const short* Bbase = (c >> 1) ? XL : XH;

  f32x4 acc[N_OUT];
  const f32x4 zz = {0.f,0.f,0.f,0.f};
#pragma unroll
  for (int o=0;o<N_OUT;o++) acc[o] = zz;

  for (int nn=0; nn<NPW; ++nn) {
    const int n = n0 + nn;
    const bf16x8 bfrag = *(const bf16x8*)&Bbase[((size_t)n*B_ + b0 + bb)*8];
    const short* Ap = &Abase[(size_t)n*1280 + bb*8];
#pragma unroll
    for (int o=0;o<N_OUT;o++) {
      const bf16x8 afrag = *(const bf16x8*)&Ap[o*128];
      acc[o] = __builtin_amdgcn_mfma_f32_16x16x32_bf16(afrag, bfrag, acc[o], 0,0,0);
    }
  }

  if (w) {
#pragma unroll
    for (int o=0;o<N_OUT;o++) red[(w-1)*640 + o*64 + l] = acc[o];
  }
  __syncthreads();
  if (!w) {
    float* Pp = &P[(size_t)sg*SN + (size_t)(b0 + bb)*OJ + c*4];
#pragma unroll
    for (int o=0;o<N_OUT;o++) {
      acc[o] += red[o*64+l] + red[640+o*64+l] + red[1280+o*64+l];
      *(f32x4*)&Pp[o*16] = acc[o];
    }
  }
}

// ---- pass 2/3: u via MFMA, logits = u.veff (log2 domain), softmax, partial ----
__global__ __launch_bounds__(256) void caps_pass23(const short* __restrict__ WH,
                                                   const short* __restrict__ WL,
                                                   const short* __restrict__ XH,
                                                   const short* __restrict__ XL,
                                                   const float* __restrict__ veff,
                                                   float* __restrict__ P) {
  __shared__ f32x4 red[3*640];         // 30 KB, conflict-free layout
  int sg, bg; sgbg_map(blockIdx.x, sg, bg);
  const int tid = threadIdx.x, w = tid >> 6, l = tid & 63;
  const int bb = l & 15, c = l >> 4;
  const int b0 = bg * 16;
  const int n0 = sg * NPB + w * NPW;
  const short* Abase = (c & 1)  ? WL : WH;
  const short* Bbase = (c >> 1) ? XL : XH;

  f32x4 vj[N_OUT], acc[N_OUT];
  const f32x4 zz = {0.f,0.f,0.f,0.f};
  const float* vp = &veff[(size_t)(b0+bb)*OJ + c*4];
#pragma unroll
  for (int o=0;o<N_OUT;o++) { vj[o] = *(const f32x4*)&vp[o*16]; acc[o] = zz; }

  for (int nn=0; nn<NPW; ++nn) {
    const int n = n0 + nn;
    const bf16x8 bfrag = *(const bf16x8*)&Bbase[((size_t)n*B_ + b0 + bb)*8];
    const short* Ap = &Abase[(size_t)n*1280 + bb*8];
    f32x4 u[N_OUT];
#pragma unroll
    for (int o=0;o<N_OUT;o++) {
      const bf16x8 afrag = *(const bf16x8*)&Ap[o*128];
      u[o] = __builtin_amdgcn_mfma_f32_16x16x32_bf16(afrag, bfrag, zz, 0,0,0);
    }
    float ez[N_OUT], Z = 0.f;
#pragma unroll
    for (int o=0;o<N_OUT;o++) {
      float t = u[o][0]*vj[o][0] + u[o][1]*vj[o][1]
              + u[o][2]*vj[o][2] + u[o][3]*vj[o][3];
      t += __shfl_xor(t, 16);
      t += __shfl_xor(t, 32);
      ez[o] = exp2f(t);                // veff already in log2 domain
      Z += ez[o];
    }
    const float invZ = __builtin_amdgcn_rcpf(Z);   // approx rcp, ~1e-7 rel
#pragma unroll
    for (int o=0;o<N_OUT;o++) acc[o] += (ez[o] * invZ) * u[o];
  }

  if (w) {
#pragma unroll
    for (int o=0;o<N_OUT;o++) red[(w-1)*640 + o*64 + l] = acc[o];
  }
  __syncthreads();
  if (!w) {
    float* Pp = &P[(size_t)sg*SN + (size_t)(b0 + bb)*OJ + c*4];
#pragma unroll
    for (int o=0;o<N_OUT;o++) {
      acc[o] += red[o*64+l] + red[640+o*64+l] + red[1280+o*64+l];
      *(f32x4*)&Pp[o*16] = acc[o];
    }
  }
}

// ---- reduce partials over NSG + squash (+ optional vprev, output scaling) ----
__global__ __launch_bounds__(256) void caps_finish(const float* __restrict__ P, float scale,
                                                   const float* __restrict__ vprev,
                                                   float* __restrict__ vout, float lscale) {
  const int idx = blockIdx.x*256 + threadIdx.x;      // b*160 + o*16 + j
  float t = 0.f;
#pragma unroll 8
  for (int g=0; g<NSG; ++g) t += P[(size_t)g*SN + idx];
  t *= scale;
  float v = squash_elem(t) * lscale;
  if (vprev != nullptr) v += vprev[idx];
  vout[idx] = v;
}

extern "C" void kernel_launch(void* const* d_in, const int* in_sizes, int n_in,
                              void* d_out, int out_size, void* d_ws, size_t ws_size,
                              hipStream_t stream) {
  const float* x = (const float*)d_in[0];   // (256,1152,8)
  const float* W = (const float*)d_in[1];   // (1,1152,10,16,8)
  float* out = (float*)d_out;               // (256,10,16)

  float* P   = (float*)d_ws;                // NSG*SN floats = 11.8 MB
  float* v1  = P  + (size_t)NSG*SN;         // stored * log2e
  float* v12 = v1 + SN;                     // stored * log2e
  short* WH = (short*)(v12 + SN);
  short* WL = WH + (size_t)NW_ELEMS*8;
  short* XH = WL + (size_t)NW_ELEMS*8;
  short* XL = XH + (size_t)NX_ELEMS*8;      // total ws ~= 27.5 MB

  pack_all<<<NWB + NTILES, 256, 0, stream>>>(W, x, WH, WL, XH, XL);

  // iter 1: uniform c -> P ; v1 = squash(0.1*s1)*log2e
  caps_pass1<<<NPASSB, 256, 0, stream>>>(WH, WL, XH, XL, P);
  caps_finish<<<SN/256, 256, 0, stream>>>(P, 0.1f, nullptr, v1, LOG2E);

  // iter 2: logits = u.v1 -> P ; v12 = v1 + squash(s2)*log2e
  caps_pass23<<<NPASSB, 256, 0, stream>>>(WH, WL, XH, XL, v1, P);
  caps_finish<<<SN/256, 256, 0, stream>>>(P, 1.0f, v1, v12, LOG2E);

  // iter 3: logits = u.v12 -> P ; out = squash(s3)
  caps_pass23<<<NPASSB, 256, 0, stream>>>(WH, WL, XH, XL, v12, P);
  caps_finish<<<SN/256, 256, 0, stream>>>(P, 1.0f, nullptr, out, 1.0f);
}

// Round 15
// 79.215 us; speedup vs baseline: 1.9476x; 1.0842x over previous
//
#include <hip/hip_runtime.h>

#define B_ 256
#define N_IN 1152
#define N_OUT 10
#define D_OUT 16
#define OJ 160                     // N_OUT * D_OUT
#define SN (B_*OJ)                 // 40960
#define LOG2E 1.44269504088896340736f
#define NPB 16                     // pass23: n's per block
#define NPW 4                      // pass23: n's per wave
#define NSG (N_IN/NPB)             // 72 partial groups for pass2/3
#define NPASSB (NSG*16)            // 1152 pass23 blocks
#define NPB1 32                    // pass1: n's per block (4-n K-packed, bf16-only)
#define NSG1 (N_IN/NPB1)           // 36 partial groups for pass1

typedef __attribute__((ext_vector_type(8))) short bf16x8;
typedef __attribute__((ext_vector_type(4))) float f32x4;

#define NW_ELEMS (N_IN*N_OUT*D_OUT)      // 184320 rows of 8 (W)
#define NX_ELEMS (B_*N_IN)               // 294912 rows of 8 (x)
#define NWB (NW_ELEMS/256)               // 720 W-pack blocks
#define NTILES ((N_IN/16)*(B_/16))       // 1152 x-transpose tiles

// ---- bf16 split helpers (RNE) ----
__device__ __forceinline__ unsigned short f2bf(float f) {
  unsigned u = __float_as_uint(f);
  u += 0x7fffu + ((u >> 16) & 1u);
  return (unsigned short)(u >> 16);
}
__device__ __forceinline__ float bf2f(unsigned short s) {
  return __uint_as_float(((unsigned)s) << 16);
}
__device__ __forceinline__ void split8(const float* p, bf16x8& vh, bf16x8& vl) {
  const float4 a = *(const float4*)p;
  const float4 b = *(const float4*)(p + 4);
  const float w[8] = {a.x,a.y,a.z,a.w,b.x,b.y,b.z,b.w};
#pragma unroll
  for (int e=0;e<8;e++){
    unsigned short hh = f2bf(w[e]);
    vh[e] = (short)hh;
    vl[e] = (short)f2bf(w[e] - bf2f(hh));
  }
}

// ---- DPP helpers ----
template<int CTRL>
__device__ __forceinline__ float dpp_add(float xx) {
  int y = __builtin_amdgcn_mov_dpp(__float_as_int(xx), CTRL, 0xF, 0xF, false);
  return xx + __int_as_float(y);
}
// full 16-row sum (finish of squash in pass-side not needed anymore)
__device__ __forceinline__ float quad_sum4(float xx) {
  xx = dpp_add<0xB1>(xx);   // quad_perm [1,0,3,2] = xor1
  xx = dpp_add<0x4E>(xx);   // quad_perm [2,3,0,1] = xor2
  return xx;                // every lane of the quad holds the 4-lane sum
}

// ---- bijective XCD-chunk swizzle (kept from R14, neutral/harmless) ----
__device__ __forceinline__ void sgbg_map(int bid, int& sg, int& bg) {
  const int xcd = bid & 7, q = bid >> 3;   // q in [0,144)
  sg = xcd*9 + (q % 9);                    // [0,72)
  bg = q / 9;                              // [0,16)
}

// ---- pack: W linear; x via LDS-transposed 16x16 tiles -> [n][b] ----
__global__ __launch_bounds__(256) void pack_all(const float* __restrict__ W,
                                                const float* __restrict__ x,
                                                short* __restrict__ WH, short* __restrict__ WL,
                                                short* __restrict__ XH, short* __restrict__ XL) {
  const int bid = blockIdx.x, tid = threadIdx.x;
  if (bid < NWB) {
    const int t = bid*256 + tid;
    bf16x8 vh, vl; split8(W + (size_t)t*8, vh, vl);
    ((bf16x8*)WH)[t] = vh; ((bf16x8*)WL)[t] = vl;
  } else {
    __shared__ bf16x8 TH[16*17], TL[16*17];
    const int tile = bid - NWB;
    const int nt = tile >> 4, bt = tile & 15;
    const int nn = tid & 15, bb = tid >> 4;        // n fastest: coalesced reads
    bf16x8 vh, vl;
    split8(x + ((size_t)(bt*16+bb)*N_IN + nt*16+nn)*8, vh, vl);
    TH[nn*17 + bb] = vh; TL[nn*17 + bb] = vl;
    __syncthreads();
    const int bb2 = tid & 15, nn2 = tid >> 4;      // b fastest: coalesced writes
    const size_t o = (size_t)(nt*16+nn2)*B_ + bt*16 + bb2;
    ((bf16x8*)XH)[o] = TH[nn2*17 + bb2];
    ((bf16x8*)XL)[o] = TL[nn2*17 + bb2];
  }
}

// ---- pass 1 (bf16-only, 4-n K-packed): acc[o] = sum_n u_h[n]  ----
// One MFMA covers 4 n's: A K-chunk c = WH[n0+c][o][j=bb][*], B K-chunk c =
// XH[n0+c][b0+bb][*]; the K=32 contraction sums over (c,i) = 4 n x 8 i.
// v1 errors (~0.5% rel) only perturb later softmax coefficients: 2nd order.
__global__ __launch_bounds__(256) void caps_pass1(const short* __restrict__ WH,
                                                  const short* __restrict__ XH,
                                                  float* __restrict__ P) {
  __shared__ f32x4 red[3*640];         // lane-contiguous 16B slots: conflict-free
  const int tid = threadIdx.x, w = tid >> 6, l = tid & 63;
  const int bb = l & 15, c = l >> 4;
  const int sg = blockIdx.x, bg = blockIdx.y;
  const int b0 = bg * 16;
  const int n0 = sg*NPB1 + w*8;        // wave covers 8 n = 2 packed groups

  f32x4 acc[N_OUT];
  const f32x4 zz = {0.f,0.f,0.f,0.f};
#pragma unroll
  for (int o=0;o<N_OUT;o++) acc[o] = zz;

#pragma unroll
  for (int grp=0; grp<2; ++grp) {
    const int nb = n0 + grp*4 + c;     // this lane's K-chunk n
    const bf16x8 bfrag = *(const bf16x8*)&XH[((size_t)nb*B_ + b0 + bb)*8];
    const short* Ap = &WH[(size_t)nb*1280 + bb*8];
#pragma unroll
    for (int o=0;o<N_OUT;o++) {
      const bf16x8 afrag = *(const bf16x8*)&Ap[o*128];
      acc[o] = __builtin_amdgcn_mfma_f32_16x16x32_bf16(afrag, bfrag, acc[o], 0,0,0);
    }
  }

  if (w) {
#pragma unroll
    for (int o=0;o<N_OUT;o++) red[(w-1)*640 + o*64 + l] = acc[o];
  }
  __syncthreads();
  if (!w) {
    float* Pp = &P[(size_t)sg*SN + (size_t)(b0 + bb)*OJ + c*4];
#pragma unroll
    for (int o=0;o<N_OUT;o++) {
      acc[o] += red[o*64+l] + red[640+o*64+l] + red[1280+o*64+l];
      *(f32x4*)&Pp[o*16] = acc[o];
    }
  }
}

// K-chunk split trick (pass2/3): A chunks [WH,WL,WH,WL], B [XH,XH,XL,XL]
// => exact (Wh+Wl)(xh+xl). C layout: col=lane&15=b, row=c*4+e=j.
__global__ __launch_bounds__(256) void caps_pass23(const short* __restrict__ WH,
                                                   const short* __restrict__ WL,
                                                   const short* __restrict__ XH,
                                                   const short* __restrict__ XL,
                                                   const float* __restrict__ veff,
                                                   float* __restrict__ P) {
  __shared__ f32x4 red[3*640];
  int sg, bg; sgbg_map(blockIdx.x, sg, bg);
  const int tid = threadIdx.x, w = tid >> 6, l = tid & 63;
  const int bb = l & 15, c = l >> 4;
  const int b0 = bg * 16;
  const int n0 = sg * NPB + w * NPW;
  const short* Abase = (c & 1)  ? WL : WH;
  const short* Bbase = (c >> 1) ? XL : XH;

  f32x4 vj[N_OUT], acc[N_OUT];
  const f32x4 zz = {0.f,0.f,0.f,0.f};
  const float* vp = &veff[(size_t)(b0+bb)*OJ + c*4];
#pragma unroll
  for (int o=0;o<N_OUT;o++) { vj[o] = *(const f32x4*)&vp[o*16]; acc[o] = zz; }

  for (int nn=0; nn<NPW; ++nn) {
    const int n = n0 + nn;
    const bf16x8 bfrag = *(const bf16x8*)&Bbase[((size_t)n*B_ + b0 + bb)*8];
    const short* Ap = &Abase[(size_t)n*1280 + bb*8];
    f32x4 u[N_OUT];
#pragma unroll
    for (int o=0;o<N_OUT;o++) {
      const bf16x8 afrag = *(const bf16x8*)&Ap[o*128];
      u[o] = __builtin_amdgcn_mfma_f32_16x16x32_bf16(afrag, bfrag, zz, 0,0,0);
    }
    float ez[N_OUT], Z = 0.f;
#pragma unroll
    for (int o=0;o<N_OUT;o++) {
      float t = u[o][0]*vj[o][0] + u[o][1]*vj[o][1]
              + u[o][2]*vj[o][2] + u[o][3]*vj[o][3];
      t += __shfl_xor(t, 16);
      t += __shfl_xor(t, 32);
      ez[o] = exp2f(t);                // veff already in log2 domain
      Z += ez[o];
    }
    const float invZ = __builtin_amdgcn_rcpf(Z);
#pragma unroll
    for (int o=0;o<N_OUT;o++) acc[o] += (ez[o] * invZ) * u[o];
  }

  if (w) {
#pragma unroll
    for (int o=0;o<N_OUT;o++) red[(w-1)*640 + o*64 + l] = acc[o];
  }
  __syncthreads();
  if (!w) {
    float* Pp = &P[(size_t)sg*SN + (size_t)(b0 + bb)*OJ + c*4];
#pragma unroll
    for (int o=0;o<N_OUT;o++) {
      acc[o] += red[o*64+l] + red[640+o*64+l] + red[1280+o*64+l];
      *(f32x4*)&Pp[o*16] = acc[o];
    }
  }
}

// ---- vectorized finish: f32x4 per thread (one j-quad), quad_perm reduce ----
// grid = SN/1024 = 40 blocks x 256 thr. Lanes 4k..4k+3 cover one (b,o) row.
template<int GC>
__global__ __launch_bounds__(256) void caps_finish(const float* __restrict__ P, float scale,
                                                   const float* __restrict__ vprev,
                                                   float* __restrict__ vout, float lscale) {
  const int e0 = (blockIdx.x*256 + threadIdx.x)*4;   // 4 consecutive elements
  f32x4 t = {0.f,0.f,0.f,0.f};
#pragma unroll 8
  for (int g=0; g<GC; ++g) t += *(const f32x4*)&P[(size_t)g*SN + e0];
  t *= scale;
  const float sq = quad_sum4(t[0]*t[0] + t[1]*t[1] + t[2]*t[2] + t[3]*t[3]);
  const float k = (sq/(1.f+sq)) * rsqrtf(sq + 1e-8f) * lscale;
  f32x4 v = t * k;
  if (vprev != nullptr) v += *(const f32x4*)&vprev[e0];
  *(f32x4*)&vout[e0] = v;
}

extern "C" void kernel_launch(void* const* d_in, const int* in_sizes, int n_in,
                              void* d_out, int out_size, void* d_ws, size_t ws_size,
                              hipStream_t stream) {
  const float* x = (const float*)d_in[0];   // (256,1152,8)
  const float* W = (const float*)d_in[1];   // (1,1152,10,16,8)
  float* out = (float*)d_out;               // (256,10,16)

  float* P   = (float*)d_ws;                // 72*SN floats = 11.8 MB (pass1 uses 36)
  float* v1  = P  + (size_t)NSG*SN;         // stored * log2e
  float* v12 = v1 + SN;                     // stored * log2e
  short* WH = (short*)(v12 + SN);
  short* WL = WH + (size_t)NW_ELEMS*8;
  short* XH = WL + (size_t)NW_ELEMS*8;
  short* XL = XH + (size_t)NX_ELEMS*8;      // total ws ~= 27.5 MB

  pack_all<<<NWB + NTILES, 256, 0, stream>>>(W, x, WH, WL, XH, XL);

  // iter 1: bf16-only 4n-packed pass -> P[36] ; v1 = squash(0.1*s1)*log2e
  caps_pass1<<<dim3(NSG1,16), 256, 0, stream>>>(WH, XH, P);
  caps_finish<NSG1><<<SN/1024, 256, 0, stream>>>(P, 0.1f, nullptr, v1, LOG2E);

  // iter 2: logits = u.v1 -> P[72] ; v12 = v1 + squash(s2)*log2e
  caps_pass23<<<NPASSB, 256, 0, stream>>>(WH, WL, XH, XL, v1, P);
  caps_finish<NSG><<<SN/1024, 256, 0, stream>>>(P, 1.0f, v1, v12, LOG2E);

  // iter 3: logits = u.v12 -> P[72] ; out = squash(s3)
  caps_pass23<<<NPASSB, 256, 0, stream>>>(WH, WL, XH, XL, v12, P);
  caps_finish<NSG><<<SN/1024, 256, 0, stream>>>(P, 1.0f, nullptr, out, 1.0f);
}